// Round 6
// baseline (17536.562 us; speedup 1.0000x reference)
//
#include <hip/hip_runtime.h>
#include <hip/hip_cooperative_groups.h>
#include <stdint.h>

// ---------------------------------------------------------------------------
// Seq2Seq (V=10000, E=256, H=512, B=64, T=128).
// Output rows are one-hot: only argmax(logits + gumbel) matters (bit-exact
// JAX threefry, partitionable XOR variant — verified R3/R4/R5, absmax 0.0).
// R6: the 510 per-step launches (≈20 µs dispatch overhead each — the real
//     bottleneck per R4/R5 A/B) are fused into 4 persistent cooperative
//     kernels with grid.sync() between steps. Step body = verified R5 body.
// ---------------------------------------------------------------------------

namespace cg = cooperative_groups;

typedef short bf16x8 __attribute__((ext_vector_type(8)));
typedef float f32x4 __attribute__((ext_vector_type(4)));

__device__ __forceinline__ void threefry2x32(uint32_t k0, uint32_t k1,
                                             uint32_t x0, uint32_t x1,
                                             uint32_t& o0, uint32_t& o1)
{
  const uint32_t k2 = k0 ^ k1 ^ 0x1BD11BDAu;
  x0 += k0; x1 += k1;
#define TF_R(r) x0 += x1; x1 = (x1 << r) | (x1 >> (32 - r)); x1 ^= x0;
  TF_R(13) TF_R(15) TF_R(26) TF_R(6)
  x0 += k1; x1 += k2 + 1u;
  TF_R(17) TF_R(29) TF_R(16) TF_R(24)
  x0 += k2; x1 += k0 + 2u;
  TF_R(13) TF_R(15) TF_R(26) TF_R(6)
  x0 += k0; x1 += k1 + 3u;
  TF_R(17) TF_R(29) TF_R(16) TF_R(24)
  x0 += k1; x1 += k2 + 4u;
  TF_R(13) TF_R(15) TF_R(26) TF_R(6)
  x0 += k2; x1 += k0 + 5u;
#undef TF_R
  o0 = x0; o1 = x1;
}

// jax.random.uniform bits, partitionable scheme, 32-bit = o0 ^ o1 (verified)
__device__ __forceinline__ float jax_uniform(uint32_t seed, uint32_t i)
{
  uint32_t o0, o1;
  threefry2x32(0u, seed, 0u, i, o0, o1);
  const uint32_t bits = o0 ^ o1;
  return __uint_as_float(0x3F800000u | (bits >> 9)) - 1.0f;
}

__device__ __forceinline__ ushort f2bf(float x)   // fp32 -> bf16 bits, RNE
{
  const uint32_t u = __float_as_uint(x);
  const uint32_t r = u + 0x7FFFu + ((u >> 16) & 1u);
  return (ushort)(r >> 16);
}
__device__ __forceinline__ float bf2f(ushort b)
{
  return __uint_as_float(((uint32_t)b) << 16);
}

__device__ __forceinline__ unsigned long long packkey(float f, int n)
{
  uint32_t u = __float_as_uint(f);
  u = (u & 0x80000000u) ? ~u : (u | 0x80000000u);   // order-preserving map
  return ((unsigned long long)u << 32) | (uint32_t)(0x7FFFFFFF - n);
}

// ---------------------------------------------------------------------------
__global__ __launch_bounds__(256)
void split_kernel(const float* __restrict__ src, ushort* __restrict__ hi,
                  ushort* __restrict__ lo, int n)
{
  const int i = blockIdx.x * 256 + threadIdx.x;
  if (i < n) {
    const float v = src[i];
    const ushort h = f2bf(v);
    hi[i] = h;
    lo[i] = f2bf(v - bf2f(h));
  }
}

// ---------------------------------------------------------------------------
// seq [t][k=512][b=64] fp32  ->  T hi/lo [t*64+b][k] bf16 (row-major M x K)
// ---------------------------------------------------------------------------
__global__ __launch_bounds__(256)
void transpose_split_kernel(const float* __restrict__ seq,
                            ushort* __restrict__ Thi, ushort* __restrict__ Tlo)
{
  __shared__ float tile[128][65];
  const int t = blockIdx.x >> 2;
  const int kc = blockIdx.x & 3;
  const int tid = threadIdx.x;
  const float* sbase = seq + (size_t)t * 32768 + (size_t)kc * 128 * 64;
#pragma unroll
  for (int it = 0; it < 32; ++it) {
    const int idx = it * 256 + tid;
    tile[idx >> 6][idx & 63] = sbase[idx];
  }
  __syncthreads();
#pragma unroll
  for (int it = 0; it < 32; ++it) {
    const int idx = it * 256 + tid;
    const int b = idx >> 7, k = idx & 127;
    const float v = tile[k][b];
    const size_t o = ((size_t)t * 64 + b) * 512 + kc * 128 + k;
    const ushort h = f2bf(v);
    Thi[o] = h;
    Tlo[o] = f2bf(v - bf2f(h));
  }
}

// ---------------------------------------------------------------------------
// Split-bf16 MFMA GEMM (verified R4). 128x128 block tile, 4 waves.
// FUSED=0: store Xg packed [t][n][b] (+bias).  FUSED=1: gumbel-argmax.
// ---------------------------------------------------------------------------
template <int GATHER, int FUSED>
__global__ __launch_bounds__(256)
void gemm_split(const ushort* __restrict__ Ahi, const ushort* __restrict__ Alo,
                const int* __restrict__ ids,
                const ushort* __restrict__ Whi, const ushort* __restrict__ Wlo,
                const float* __restrict__ bias, float* __restrict__ Xg,
                const int* __restrict__ mask, const int* __restrict__ idxmap,
                unsigned long long* __restrict__ keys,
                int M, int N, int K)
{
  const int tid = threadIdx.x;
  const int wid = tid >> 6, lane = tid & 63;
  const int lm = lane & 15, quad = lane >> 4;
  const int m0 = blockIdx.x * 128 + (wid >> 1) * 64;
  const int n0 = blockIdx.y * 128 + (wid & 1) * 64;
  const int koff = quad * 8;

  size_t offA[4];
#pragma unroll
  for (int mi = 0; mi < 4; ++mi) {
    int m = m0 + mi * 16 + lm;
    int mc = m < M ? m : (M - 1);
    if (GATHER) {
      const int tok = ids[(mc & 63) * 128 + (mc >> 6)];
      offA[mi] = (size_t)tok * K;
    } else {
      offA[mi] = (size_t)mc * K;
    }
  }
  size_t offB[4];
#pragma unroll
  for (int ni = 0; ni < 4; ++ni) {
    int n = n0 + ni * 16 + lm;
    int nc = n < N ? n : (N - 1);
    offB[ni] = (size_t)nc * K;
  }

  f32x4 acc[4][4];
#pragma unroll
  for (int mi = 0; mi < 4; ++mi)
#pragma unroll
    for (int ni = 0; ni < 4; ++ni) acc[mi][ni] = (f32x4){0.f, 0.f, 0.f, 0.f};

  for (int k0 = 0; k0 < K; k0 += 32) {
    bf16x8 ah[4], al[4];
#pragma unroll
    for (int mi = 0; mi < 4; ++mi) {
      ah[mi] = *(const bf16x8*)(Ahi + offA[mi] + k0 + koff);
      al[mi] = *(const bf16x8*)(Alo + offA[mi] + k0 + koff);
    }
#pragma unroll
    for (int ni = 0; ni < 4; ++ni) {
      const bf16x8 bh = *(const bf16x8*)(Whi + offB[ni] + k0 + koff);
      const bf16x8 bl = *(const bf16x8*)(Wlo + offB[ni] + k0 + koff);
#pragma unroll
      for (int mi = 0; mi < 4; ++mi) {
        acc[mi][ni] = __builtin_amdgcn_mfma_f32_16x16x32_bf16(ah[mi], bl, acc[mi][ni], 0, 0, 0);
        acc[mi][ni] = __builtin_amdgcn_mfma_f32_16x16x32_bf16(al[mi], bh, acc[mi][ni], 0, 0, 0);
        acc[mi][ni] = __builtin_amdgcn_mfma_f32_16x16x32_bf16(ah[mi], bh, acc[mi][ni], 0, 0, 0);
      }
    }
  }

  float bv[4];
#pragma unroll
  for (int ni = 0; ni < 4; ++ni) {
    int n = n0 + ni * 16 + lm;
    bv[ni] = bias[n < N ? n : (N - 1)];
  }

  if (FUSED == 0) {
#pragma unroll
    for (int mi = 0; mi < 4; ++mi) {
#pragma unroll
      for (int i = 0; i < 4; ++i) {
        const int m = m0 + mi * 16 + quad * 4 + i;
        if (m >= M) continue;
        const int t = m >> 6, b = m & 63;
        float* base = Xg + (size_t)t * 131072 + b;
#pragma unroll
        for (int ni = 0; ni < 4; ++ni) {
          const int n = n0 + ni * 16 + lm;
          base[(size_t)n * 64] = acc[mi][ni][i] + bv[ni];
        }
      }
    }
  } else {
#pragma unroll
    for (int mi = 0; mi < 4; ++mi) {
#pragma unroll
      for (int i = 0; i < 4; ++i) {
        const int m = m0 + mi * 16 + quad * 4 + i;
        if (m >= M) continue;
        const int j = m >> 6, b = m & 63;
        const int outrow = b * 128 + j + 1;
        if (mask[outrow] == 0) continue;
        const int r = idxmap[outrow];
        const uint32_t base7 = (uint32_t)(r * 64 + b) * 10000u;
        float best = -3.0e38f;
        int bestn = 0;
#pragma unroll
        for (int ni = 0; ni < 4; ++ni) {
          const int n = n0 + ni * 16 + lm;
          if (n < N) {
            const float u7 = jax_uniform(7u, base7 + (uint32_t)n);
            const float g = -logf(-logf(u7 + 1e-20f) + 1e-20f);
            const float z = acc[mi][ni][i] + bv[ni] + g;
            if (z > best) { best = z; bestn = n; }
          }
        }
        unsigned long long key = packkey(best, bestn);
#pragma unroll
        for (int s = 1; s < 16; s <<= 1) {
          const unsigned long long o = __shfl_xor(key, s, 64);
          if (o > key) key = o;
        }
        if (lm == 0) atomicMax(keys + outrow, key);
      }
    }
  }
}

// ---------------------------------------------------------------------------
// R6: persistent LSTM layer — the R5-verified MFMA step body looped nsteps
// times inside ONE cooperative kernel. 32 blocks x 256 thr; wave mi handles
// batches [mi*16,mi*16+16), block handles units [U0,U0+16) x 4 gates.
// h carried as bf16 split in A-fragment layout hs[b][k=u]; ping-pong X<->Y
// (t even: read X write Y). Whh pre-split bf16 hi/lo [2048][512], L2-resident.
// grid.sync() + device fence between steps (cross-XCD visibility).
// ---------------------------------------------------------------------------
__global__ __launch_bounds__(256)
void lstm_layer_coop(const float* __restrict__ Xg,
                     const ushort* __restrict__ WHi, const ushort* __restrict__ WLo,
                     float* __restrict__ cstate, float* __restrict__ seq_out,
                     ushort* __restrict__ hXhi, ushort* __restrict__ hXlo,
                     ushort* __restrict__ hYhi, ushort* __restrict__ hYlo,
                     int nsteps)
{
  cg::grid_group grid = cg::this_grid();

  const int tid = threadIdx.x;
  const int mi = tid >> 6;
  const int lane = tid & 63;
  const int lm = lane & 15, quad = lane >> 4;
  const int u = blockIdx.x * 16 + lm;
  const int koff = quad * 8;
  const int b0 = mi * 16 + quad * 4;

  const size_t aoff = (size_t)(mi * 16 + lm) * 512 + koff;
  const ushort* bH[4];
  const ushort* bL[4];
#pragma unroll
  for (int g = 0; g < 4; ++g) {
    const size_t o = (size_t)(g * 512 + u) * 512 + koff;
    bH[g] = WHi + o;
    bL[g] = WLo + o;
  }
  float* cptr = cstate + (size_t)u * 64 + b0;

  for (int t = 0; t < nsteps; ++t) {
    const ushort* iHi = (t & 1) ? hYhi : hXhi;
    const ushort* iLo = (t & 1) ? hYlo : hXlo;
    ushort* oHi = (t & 1) ? hXhi : hYhi;
    ushort* oLo = (t & 1) ? hXlo : hYlo;

    const ushort* aHi = iHi + aoff;
    const ushort* aLo = iLo + aoff;

    f32x4 acc[4];
#pragma unroll
    for (int g = 0; g < 4; ++g) acc[g] = (f32x4){0.f, 0.f, 0.f, 0.f};

#pragma unroll 4
    for (int k0 = 0; k0 < 512; k0 += 32) {
      const bf16x8 ah = *(const bf16x8*)(aHi + k0);
      const bf16x8 al = *(const bf16x8*)(aLo + k0);
#pragma unroll
      for (int g = 0; g < 4; ++g) {
        const bf16x8 bh = *(const bf16x8*)(bH[g] + k0);
        const bf16x8 bl = *(const bf16x8*)(bL[g] + k0);
        acc[g] = __builtin_amdgcn_mfma_f32_16x16x32_bf16(ah, bl, acc[g], 0, 0, 0);
        acc[g] = __builtin_amdgcn_mfma_f32_16x16x32_bf16(al, bh, acc[g], 0, 0, 0);
        acc[g] = __builtin_amdgcn_mfma_f32_16x16x32_bf16(ah, bh, acc[g], 0, 0, 0);
      }
    }

    // epilogue: lane owns unit u, batches b0..b0+3
    const float* Xt = Xg + (size_t)t * 131072;
    const float4 xi = *(const float4*)(Xt + (size_t)(0 * 512 + u) * 64 + b0);
    const float4 xf = *(const float4*)(Xt + (size_t)(1 * 512 + u) * 64 + b0);
    const float4 xg = *(const float4*)(Xt + (size_t)(2 * 512 + u) * 64 + b0);
    const float4 xo = *(const float4*)(Xt + (size_t)(3 * 512 + u) * 64 + b0);
    float4 c4 = *(float4*)cptr;

    float4 h4;
#pragma unroll
    for (int r = 0; r < 4; ++r) {
      const float zi = acc[0][r] + ((const float*)&xi)[r];
      const float zf = acc[1][r] + ((const float*)&xf)[r];
      const float zg = acc[2][r] + ((const float*)&xg)[r];
      const float zo = acc[3][r] + ((const float*)&xo)[r];
      const float I = 1.0f / (1.0f + expf(-zi));
      const float F = 1.0f / (1.0f + expf(-zf));
      const float G = tanhf(zg);
      const float O = 1.0f / (1.0f + expf(-zo));
      const float cn = F * ((float*)&c4)[r] + I * G;
      ((float*)&c4)[r] = cn;
      ((float*)&h4)[r] = O * tanhf(cn);
    }
    *(float4*)cptr = c4;
    *(float4*)(seq_out + (size_t)t * 32768 + (size_t)u * 64 + b0) = h4;
#pragma unroll
    for (int r = 0; r < 4; ++r) {
      const float hv = ((const float*)&h4)[r];
      const ushort hh = f2bf(hv);
      oHi[(size_t)(b0 + r) * 512 + u] = hh;
      oLo[(size_t)(b0 + r) * 512 + u] = f2bf(hv - bf2f(hh));
    }

    __threadfence();   // device-scope: make h visible across XCDs
    grid.sync();
  }
}

// ---------------------------------------------------------------------------
__global__ void maskscan_kernel(const int* __restrict__ mask,
                                int* __restrict__ idxmap)
{
  const int b = threadIdx.x;   // 64 threads
  int run = 0;
  for (int t = 0; t < 128; ++t) {
    idxmap[b * 128 + t] = run;
    run += mask[b * 128 + t];
  }
}

__global__ __launch_bounds__(256)
void t0_kernel(const int* __restrict__ mask, unsigned long long* __restrict__ keys)
{
  const int b = blockIdx.x;
  const int row = b * 128;
  if (mask[row] == 0) return;
  const int tid = threadIdx.x;
  const uint32_t base = (uint32_t)b * 10000u;
  float best = -3.0e38f;
  int bestn = 0;
  for (int v = tid; v < 10000; v += 256) {
    const float u42 = jax_uniform(42u, base + (uint32_t)v);
    const float u7 = jax_uniform(7u, base + (uint32_t)v);
    const float g = -logf(-logf(u7 + 1e-20f) + 1e-20f);
    const float z = u42 + g;
    if (z > best) { best = z; bestn = v; }
  }
  __shared__ unsigned long long sk[256];
  sk[tid] = packkey(best, bestn);
  __syncthreads();
  for (int s = 128; s > 0; s >>= 1) {
    if (tid < s) { if (sk[tid + s] > sk[tid]) sk[tid] = sk[tid + s]; }
    __syncthreads();
  }
  if (tid == 0) keys[row] = sk[0];
}

__global__ __launch_bounds__(256)
void finalize_kernel(const unsigned long long* __restrict__ keys,
                     const int* __restrict__ mask,
                     const int* __restrict__ input_ids,
                     int* __restrict__ tokens)
{
  const int row = blockIdx.x * 256 + threadIdx.x;
  if (row < 8192) {
    tokens[row] = mask[row] ? (int)(0x7FFFFFFFu - (uint32_t)(keys[row] & 0xFFFFFFFFu))
                            : input_ids[row];
  }
}

__global__ __launch_bounds__(256)
void onehot_kernel(const int* __restrict__ tokens, float* __restrict__ out)
{
  const int row = blockIdx.x;
  const int tok = tokens[row];
  float4* orow = (float4*)(out + (size_t)row * 10000);
  for (int q = threadIdx.x; q < 2500; q += 256) {
    float4 v = make_float4(0.f, 0.f, 0.f, 0.f);
    const int v0 = q << 2;
    const unsigned d = (unsigned)(tok - v0);
    if (d < 4u) ((float*)&v)[d] = 1.0f;
    orow[q] = v;
  }
}

__global__ __launch_bounds__(256)
void zero_kernel(float* __restrict__ p, int n)
{
  const int i = blockIdx.x * 256 + threadIdx.x;
  if (i < n) p[i] = 0.f;
}

// ---------------------------------------------------------------------------
extern "C" void kernel_launch(void* const* d_in, const int* in_sizes, int n_in,
                              void* d_out, int out_size, void* d_ws, size_t ws_size,
                              hipStream_t stream)
{
  const int*   input_ids = (const int*)d_in[0];
  const int*   mask      = (const int*)d_in[1];
  const float* enc_embed = (const float*)d_in[3];
  const float* enc_Wih0  = (const float*)d_in[4];
  const float* enc_Whh0  = (const float*)d_in[5];
  const float* enc_b0    = (const float*)d_in[6];
  const float* enc_Wih1  = (const float*)d_in[7];
  const float* enc_Whh1  = (const float*)d_in[8];
  const float* enc_b1    = (const float*)d_in[9];
  const float* dec_embed = (const float*)d_in[10];
  const float* dec_Wih0  = (const float*)d_in[11];
  const float* dec_Whh0  = (const float*)d_in[12];
  const float* dec_b0    = (const float*)d_in[13];
  const float* dec_Wih1  = (const float*)d_in[14];
  const float* dec_Whh1  = (const float*)d_in[15];
  const float* dec_b1    = (const float*)d_in[16];
  const float* dec_Wout  = (const float*)d_in[17];
  const float* dec_bout  = (const float*)d_in[18];

  // ---- d_out doubles as scratch (327.68 MB); all dead before onehot ----
  char* O = (char*)d_out;
  float*  Xg    = (float*)(O + 0);                    // 8192*2048 f32
  ushort* sThi  = (ushort*)(O + 67108864);
  ushort* sTlo  = (ushort*)(O + 75497472);
  ushort* eEh   = (ushort*)(O + 83886080);
  ushort* eEl   = (ushort*)(O + 89006080);
  ushort* dEh   = (ushort*)(O + 94126080);
  ushort* dEl   = (ushort*)(O + 99246080);
  ushort* eW0h  = (ushort*)(O + 104366080);
  ushort* eW0l  = (ushort*)(O + 105414656);
  ushort* eW1h  = (ushort*)(O + 106463232);
  ushort* eW1l  = (ushort*)(O + 108560384);
  ushort* dW0h  = (ushort*)(O + 110657536);
  ushort* dW0l  = (ushort*)(O + 111706112);
  ushort* dW1h  = (ushort*)(O + 112754688);
  ushort* dW1l  = (ushort*)(O + 114851840);
  ushort* Woh   = (ushort*)(O + 116948992);
  ushort* Wol   = (ushort*)(O + 127188992);
  unsigned long long* keys = (unsigned long long*)(O + 137428992);
  int*    idxmap = (int*)(O + 137494528);
  // Whh splits (each 2,097,152 B)
  ushort* eH0h = (ushort*)(O + 137527296);
  ushort* eH0l = (ushort*)(O + 139624448);
  ushort* eH1h = (ushort*)(O + 141721600);
  ushort* eH1l = (ushort*)(O + 143818752);
  ushort* dH0h = (ushort*)(O + 145915904);
  ushort* dH0l = (ushort*)(O + 148013056);
  ushort* dH1h = (ushort*)(O + 150110208);
  ushort* dH1l = (ushort*)(O + 152207360);
  // h-split state buffers, 65,536 B each, contiguous (zeroed in one shot)
  ushort* hsAhi = (ushort*)(O + 154304512);
  ushort* hsAlo = (ushort*)(O + 154370048);
  ushort* hsBhi = (ushort*)(O + 154435584);
  ushort* hsBlo = (ushort*)(O + 154501120);
  ushort* hsChi = (ushort*)(O + 154566656);
  ushort* hsClo = (ushort*)(O + 154632192);
  ushort* hsDhi = (ushort*)(O + 154697728);
  ushort* hsDlo = (ushort*)(O + 154763264);

  // ---- workspace ----
  float* seqA = (float*)d_ws;                         // 128*32768 f32
  float* zbuf = seqA + (size_t)128 * 32768;           // (layout keep)
  float* cA   = zbuf + 32768;
  float* cB   = cA + 32768;
  float* hp0  = cB + 32768;                           // dummy seq_out (enc L1)
  float* hp1  = hp0 + 32768;
  int* tokens = (int*)(hp1 + 32768);

  zero_kernel<<<256, 256, 0, stream>>>(cA, 2 * 32768);           // cA, cB
  zero_kernel<<<512, 256, 0, stream>>>((float*)hsAhi, 131072);   // all hs bufs
  zero_kernel<<<64, 256, 0, stream>>>((float*)keys, 16384);
  maskscan_kernel<<<1, 64, 0, stream>>>(mask, idxmap);

  // ---- one-shot precision splits ----
  split_kernel<<<10000, 256, 0, stream>>>(enc_embed, eEh, eEl, 2560000);
  split_kernel<<<10000, 256, 0, stream>>>(dec_embed, dEh, dEl, 2560000);
  split_kernel<<<2048, 256, 0, stream>>>(enc_Wih0, eW0h, eW0l, 524288);
  split_kernel<<<4096, 256, 0, stream>>>(enc_Wih1, eW1h, eW1l, 1048576);
  split_kernel<<<2048, 256, 0, stream>>>(dec_Wih0, dW0h, dW0l, 524288);
  split_kernel<<<4096, 256, 0, stream>>>(dec_Wih1, dW1h, dW1l, 1048576);
  split_kernel<<<20000, 256, 0, stream>>>(dec_Wout, Woh, Wol, 5120000);
  split_kernel<<<4096, 256, 0, stream>>>(enc_Whh0, eH0h, eH0l, 1048576);
  split_kernel<<<4096, 256, 0, stream>>>(enc_Whh1, eH1h, eH1l, 1048576);
  split_kernel<<<4096, 256, 0, stream>>>(dec_Whh0, dH0h, dH0l, 1048576);
  split_kernel<<<4096, 256, 0, stream>>>(dec_Whh1, dH1h, dH1l, 1048576);

  int nsteps128 = 128, nsteps127 = 127;

  // ---- encoder layer 0: chain A<->B (even t reads A), final lands in A ----
  gemm_split<1, 0><<<dim3(64, 16), 256, 0, stream>>>(
      eEh, eEl, input_ids, eW0h, eW0l, enc_b0, Xg,
      nullptr, nullptr, nullptr, 8192, 2048, 256);
  {
    const float* a0 = Xg; const ushort* a1 = eH0h; const ushort* a2 = eH0l;
    float* a3 = cA; float* a4 = seqA;
    ushort* a5 = hsAhi; ushort* a6 = hsAlo; ushort* a7 = hsBhi; ushort* a8 = hsBlo;
    void* args[] = {&a0, &a1, &a2, &a3, &a4, &a5, &a6, &a7, &a8, &nsteps128};
    hipLaunchCooperativeKernel((void*)lstm_layer_coop, dim3(32), dim3(256),
                               args, 0, stream);
  }

  // ---- encoder layer 1: chain C<->D, final lands in C ----
  transpose_split_kernel<<<512, 256, 0, stream>>>(seqA, sThi, sTlo);
  gemm_split<0, 0><<<dim3(64, 16), 256, 0, stream>>>(
      sThi, sTlo, nullptr, eW1h, eW1l, enc_b1, Xg,
      nullptr, nullptr, nullptr, 8192, 2048, 512);
  {
    const float* a0 = Xg; const ushort* a1 = eH1h; const ushort* a2 = eH1l;
    float* a3 = cB; float* a4 = hp0;   // seq not needed; hp0 = 1-step dummy? no:
    // hp0 is only 32768 floats but seq_out indexes t*32768 — use seqA-sized
    // dummy region: reuse Xg? Xg is live (read this launch). Use seqA is live
    // too (read by transpose BEFORE this — done already). seqA is dead now:
    a4 = seqA;                          // overwritten; re-filled by dec L0
    ushort* a5 = hsChi; ushort* a6 = hsClo; ushort* a7 = hsDhi; ushort* a8 = hsDlo;
    void* args[] = {&a0, &a1, &a2, &a3, &a4, &a5, &a6, &a7, &a8, &nsteps128};
    hipLaunchCooperativeKernel((void*)lstm_layer_coop, dim3(32), dim3(256),
                               args, 0, stream);
  }

  // ---- decoder layer 0: init h = enc L0 final (hsA), c = cA; 127 steps ----
  gemm_split<1, 0><<<dim3(64, 16), 256, 0, stream>>>(
      dEh, dEl, input_ids, dW0h, dW0l, dec_b0, Xg,
      nullptr, nullptr, nullptr, 8128, 2048, 256);
  {
    const float* a0 = Xg; const ushort* a1 = dH0h; const ushort* a2 = dH0l;
    float* a3 = cA; float* a4 = seqA;
    ushort* a5 = hsAhi; ushort* a6 = hsAlo; ushort* a7 = hsBhi; ushort* a8 = hsBlo;
    void* args[] = {&a0, &a1, &a2, &a3, &a4, &a5, &a6, &a7, &a8, &nsteps127};
    hipLaunchCooperativeKernel((void*)lstm_layer_coop, dim3(32), dim3(256),
                               args, 0, stream);
  }

  // ---- decoder layer 1: init h = enc L1 final (hsC), c = cB; 127 steps ----
  transpose_split_kernel<<<508, 256, 0, stream>>>(seqA, sThi, sTlo);
  gemm_split<0, 0><<<dim3(64, 16), 256, 0, stream>>>(
      sThi, sTlo, nullptr, dW1h, dW1l, dec_b1, Xg,
      nullptr, nullptr, nullptr, 8128, 2048, 512);
  {
    const float* a0 = Xg; const ushort* a1 = dH1h; const ushort* a2 = dH1l;
    float* a3 = cB; float* a4 = seqA;
    ushort* a5 = hsChi; ushort* a6 = hsClo; ushort* a7 = hsDhi; ushort* a8 = hsDlo;
    void* args[] = {&a0, &a1, &a2, &a3, &a4, &a5, &a6, &a7, &a8, &nsteps127};
    hipLaunchCooperativeKernel((void*)lstm_layer_coop, dim3(32), dim3(256),
                               args, 0, stream);
  }

  // ---- fused logits + gumbel-argmax (no logits materialization) ----
  transpose_split_kernel<<<508, 256, 0, stream>>>(seqA, sThi, sTlo);
  gemm_split<0, 1><<<dim3(64, 79), 256, 0, stream>>>(
      sThi, sTlo, nullptr, Woh, Wol, dec_bout, nullptr,
      mask, idxmap, keys, 8128, 10000, 512);
  t0_kernel<<<64, 256, 0, stream>>>(mask, keys);

  // ---- tokens -> one-hot output ----
  finalize_kernel<<<32, 256, 0, stream>>>(keys, mask, input_ids, tokens);
  onehot_kernel<<<8192, 256, 0, stream>>>(tokens, (float*)d_out);
}

// Round 7
// 13560.231 us; speedup vs baseline: 1.2932x; 1.2932x over previous
//
#include <hip/hip_runtime.h>
#include <stdint.h>

// ---------------------------------------------------------------------------
// Seq2Seq (V=10000, E=256, H=512, B=64, T=128).
// Output rows are one-hot: only argmax(logits + gumbel) matters (bit-exact
// JAX threefry, partitionable XOR variant — verified R3..R6, absmax 0.0).
// R7: cg::grid.sync() measured at ~31 µs/step (R6 profile: 3.96 ms/layer,
//     occupancy 1.5%) -> replaced with hand-rolled monotonic spin barrier
//     (~2 µs/step expected). Persist kernel also emits seqT (bf16 split,
//     GEMM-A layout) directly -> transpose kernels deleted. All split/zero
//     prep fused into one kernel. 14 launches total.
// ---------------------------------------------------------------------------

typedef short bf16x8 __attribute__((ext_vector_type(8)));
typedef float f32x4 __attribute__((ext_vector_type(4)));

__device__ __forceinline__ void threefry2x32(uint32_t k0, uint32_t k1,
                                             uint32_t x0, uint32_t x1,
                                             uint32_t& o0, uint32_t& o1)
{
  const uint32_t k2 = k0 ^ k1 ^ 0x1BD11BDAu;
  x0 += k0; x1 += k1;
#define TF_R(r) x0 += x1; x1 = (x1 << r) | (x1 >> (32 - r)); x1 ^= x0;
  TF_R(13) TF_R(15) TF_R(26) TF_R(6)
  x0 += k1; x1 += k2 + 1u;
  TF_R(17) TF_R(29) TF_R(16) TF_R(24)
  x0 += k2; x1 += k0 + 2u;
  TF_R(13) TF_R(15) TF_R(26) TF_R(6)
  x0 += k0; x1 += k1 + 3u;
  TF_R(17) TF_R(29) TF_R(16) TF_R(24)
  x0 += k1; x1 += k2 + 4u;
  TF_R(13) TF_R(15) TF_R(26) TF_R(6)
  x0 += k2; x1 += k0 + 5u;
#undef TF_R
  o0 = x0; o1 = x1;
}

// jax.random.uniform bits, partitionable scheme, 32-bit = o0 ^ o1 (verified)
__device__ __forceinline__ float jax_uniform(uint32_t seed, uint32_t i)
{
  uint32_t o0, o1;
  threefry2x32(0u, seed, 0u, i, o0, o1);
  const uint32_t bits = o0 ^ o1;
  return __uint_as_float(0x3F800000u | (bits >> 9)) - 1.0f;
}

__device__ __forceinline__ ushort f2bf(float x)   // fp32 -> bf16 bits, RNE
{
  const uint32_t u = __float_as_uint(x);
  const uint32_t r = u + 0x7FFFu + ((u >> 16) & 1u);
  return (ushort)(r >> 16);
}
__device__ __forceinline__ float bf2f(ushort b)
{
  return __uint_as_float(((uint32_t)b) << 16);
}

__device__ __forceinline__ unsigned long long packkey(float f, int n)
{
  uint32_t u = __float_as_uint(f);
  u = (u & 0x80000000u) ? ~u : (u | 0x80000000u);   // order-preserving map
  return ((unsigned long long)u << 32) | (uint32_t)(0x7FFFFFFF - n);
}

// ---- d_out scratch layout (byte offsets), shared host/device -------------
#define OFF_XG        0
#define OFF_STHI      67108864
#define OFF_STLO      75497472
#define OFF_EEH       83886080
#define OFF_EEL       89006080
#define OFF_DEH       94126080
#define OFF_DEL       99246080
#define OFF_EW0H      104366080
#define OFF_EW0L      105414656
#define OFF_EW1H      106463232
#define OFF_EW1L      108560384
#define OFF_DW0H      110657536
#define OFF_DW0L      111706112
#define OFF_DW1H      112754688
#define OFF_DW1L      114851840
#define OFF_WOH       116948992
#define OFF_WOL       127188992
#define OFF_KEYS      137428992
#define OFF_IDXMAP    137494528
#define OFF_EH0H      137527296
#define OFF_EH0L      139624448
#define OFF_EH1H      141721600
#define OFF_EH1L      143818752
#define OFF_DH0H      145915904
#define OFF_DH0L      148013056
#define OFF_DH1H      150110208
#define OFF_DH1L      152207360
#define OFF_HSA_HI    154304512
#define OFF_HSA_LO    154370048
#define OFF_HSB_HI    154435584
#define OFF_HSB_LO    154501120
#define OFF_HSC_HI    154566656
#define OFF_HSC_LO    154632192
#define OFF_HSD_HI    154697728
#define OFF_HSD_LO    154763264
#define OFF_BARS      154828800

// ---------------------------------------------------------------------------
// prep: all 11 fp32->bf16(hi,lo) splits + all zero-inits in ONE kernel.
// Split segs: 68672 blocks; zeros: keys 64, hs 512, bars 1, cA/cB(ws) 256.
// ---------------------------------------------------------------------------
__global__ __launch_bounds__(256)
void prep_kernel(char* __restrict__ O, float* __restrict__ ws,
                 const float* s0, const float* s1, const float* s2,
                 const float* s3, const float* s4, const float* s5,
                 const float* s6, const float* s7, const float* s8,
                 const float* s9, const float* s10)
{
  const int tid = threadIdx.x;
  const int b = blockIdx.x;
  if (b < 68672) {
    const int n[11] = {2560000,2560000,524288,1048576,524288,1048576,
                       5120000,1048576,1048576,1048576,1048576};
    const int cum[11] = {0,10000,20000,22048,26144,28192,32288,
                         52288,56384,60480,64576};
    const int offh[11] = {OFF_EEH,OFF_DEH,OFF_EW0H,OFF_EW1H,OFF_DW0H,OFF_DW1H,
                          OFF_WOH,OFF_EH0H,OFF_EH1H,OFF_DH0H,OFF_DH1H};
    const int offl[11] = {OFF_EEL,OFF_DEL,OFF_EW0L,OFF_EW1L,OFF_DW0L,OFF_DW1L,
                          OFF_WOL,OFF_EH0L,OFF_EH1L,OFF_DH0L,OFF_DH1L};
    const float* srcs[11] = {s0,s1,s2,s3,s4,s5,s6,s7,s8,s9,s10};
    int seg = 10;
#pragma unroll
    for (int s = 0; s < 10; ++s)
      if (b >= cum[s] && b < cum[s + 1]) seg = s;
    const int i = (b - cum[seg]) * 256 + tid;
    if (i < n[seg]) {
      const float v = srcs[seg][i];
      const ushort h = f2bf(v);
      ((ushort*)(O + offh[seg]))[i] = h;
      ((ushort*)(O + offl[seg]))[i] = f2bf(v - bf2f(h));
    }
  } else if (b < 68736) {            // keys: 16384 uints
    ((unsigned*)(O + OFF_KEYS))[(b - 68672) * 256 + tid] = 0u;
  } else if (b < 69248) {            // hs bufs: 131072 uints (8 x 64KB)
    ((unsigned*)(O + OFF_HSA_HI))[(b - 68736) * 256 + tid] = 0u;
  } else if (b == 69248) {           // barrier counters
    if (tid < 16) ((unsigned*)(O + OFF_BARS))[tid] = 0u;
  } else {                           // cA/cB in ws: 65536 floats
    ws[(b - 69249) * 256 + tid] = 0.0f;
  }
}

// ---------------------------------------------------------------------------
// Split-bf16 MFMA GEMM (verified R4). 128x128 block tile, 4 waves.
// FUSED=0: store Xg packed [t][n][b] (+bias).  FUSED=1: gumbel-argmax.
// ---------------------------------------------------------------------------
template <int GATHER, int FUSED>
__global__ __launch_bounds__(256)
void gemm_split(const ushort* __restrict__ Ahi, const ushort* __restrict__ Alo,
                const int* __restrict__ ids,
                const ushort* __restrict__ Whi, const ushort* __restrict__ Wlo,
                const float* __restrict__ bias, float* __restrict__ Xg,
                const int* __restrict__ mask, const int* __restrict__ idxmap,
                unsigned long long* __restrict__ keys,
                int M, int N, int K)
{
  const int tid = threadIdx.x;
  const int wid = tid >> 6, lane = tid & 63;
  const int lm = lane & 15, quad = lane >> 4;
  const int m0 = blockIdx.x * 128 + (wid >> 1) * 64;
  const int n0 = blockIdx.y * 128 + (wid & 1) * 64;
  const int koff = quad * 8;

  size_t offA[4];
#pragma unroll
  for (int mi = 0; mi < 4; ++mi) {
    int m = m0 + mi * 16 + lm;
    int mc = m < M ? m : (M - 1);
    if (GATHER) {
      const int tok = ids[(mc & 63) * 128 + (mc >> 6)];
      offA[mi] = (size_t)tok * K;
    } else {
      offA[mi] = (size_t)mc * K;
    }
  }
  size_t offB[4];
#pragma unroll
  for (int ni = 0; ni < 4; ++ni) {
    int n = n0 + ni * 16 + lm;
    int nc = n < N ? n : (N - 1);
    offB[ni] = (size_t)nc * K;
  }

  f32x4 acc[4][4];
#pragma unroll
  for (int mi = 0; mi < 4; ++mi)
#pragma unroll
    for (int ni = 0; ni < 4; ++ni) acc[mi][ni] = (f32x4){0.f, 0.f, 0.f, 0.f};

  for (int k0 = 0; k0 < K; k0 += 32) {
    bf16x8 ah[4], al[4];
#pragma unroll
    for (int mi = 0; mi < 4; ++mi) {
      ah[mi] = *(const bf16x8*)(Ahi + offA[mi] + k0 + koff);
      al[mi] = *(const bf16x8*)(Alo + offA[mi] + k0 + koff);
    }
#pragma unroll
    for (int ni = 0; ni < 4; ++ni) {
      const bf16x8 bh = *(const bf16x8*)(Whi + offB[ni] + k0 + koff);
      const bf16x8 bl = *(const bf16x8*)(Wlo + offB[ni] + k0 + koff);
#pragma unroll
      for (int mi = 0; mi < 4; ++mi) {
        acc[mi][ni] = __builtin_amdgcn_mfma_f32_16x16x32_bf16(ah[mi], bl, acc[mi][ni], 0, 0, 0);
        acc[mi][ni] = __builtin_amdgcn_mfma_f32_16x16x32_bf16(al[mi], bh, acc[mi][ni], 0, 0, 0);
        acc[mi][ni] = __builtin_amdgcn_mfma_f32_16x16x32_bf16(ah[mi], bh, acc[mi][ni], 0, 0, 0);
      }
    }
  }

  float bv[4];
#pragma unroll
  for (int ni = 0; ni < 4; ++ni) {
    int n = n0 + ni * 16 + lm;
    bv[ni] = bias[n < N ? n : (N - 1)];
  }

  if (FUSED == 0) {
#pragma unroll
    for (int mi = 0; mi < 4; ++mi) {
#pragma unroll
      for (int i = 0; i < 4; ++i) {
        const int m = m0 + mi * 16 + quad * 4 + i;
        if (m >= M) continue;
        const int t = m >> 6, b = m & 63;
        float* base = Xg + (size_t)t * 131072 + b;
#pragma unroll
        for (int ni = 0; ni < 4; ++ni) {
          const int n = n0 + ni * 16 + lm;
          base[(size_t)n * 64] = acc[mi][ni][i] + bv[ni];
        }
      }
    }
  } else {
#pragma unroll
    for (int mi = 0; mi < 4; ++mi) {
#pragma unroll
      for (int i = 0; i < 4; ++i) {
        const int m = m0 + mi * 16 + quad * 4 + i;
        if (m >= M) continue;
        const int j = m >> 6, b = m & 63;
        const int outrow = b * 128 + j + 1;
        if (mask[outrow] == 0) continue;
        const int r = idxmap[outrow];
        const uint32_t base7 = (uint32_t)(r * 64 + b) * 10000u;
        float best = -3.0e38f;
        int bestn = 0;
#pragma unroll
        for (int ni = 0; ni < 4; ++ni) {
          const int n = n0 + ni * 16 + lm;
          if (n < N) {
            const float u7 = jax_uniform(7u, base7 + (uint32_t)n);
            const float g = -logf(-logf(u7 + 1e-20f) + 1e-20f);
            const float z = acc[mi][ni][i] + bv[ni] + g;
            if (z > best) { best = z; bestn = n; }
          }
        }
        unsigned long long key = packkey(best, bestn);
#pragma unroll
        for (int s = 1; s < 16; s <<= 1) {
          const unsigned long long o = __shfl_xor(key, s, 64);
          if (o > key) key = o;
        }
        if (lm == 0) atomicMax(keys + outrow, key);
      }
    }
  }
}

// ---------------------------------------------------------------------------
// Hand-rolled grid barrier: monotonic arrival counter (no reset races).
// Release fence -> arrive -> spin (agent-scope load) -> acquire fence.
// __syncthreads at entry drains each wave's loads before arrival (s_barrier
// implies vmcnt drain), so double-buffer + single barrier per step is safe.
// ---------------------------------------------------------------------------
__device__ __forceinline__ void grid_bar(unsigned* cnt, unsigned target)
{
  __syncthreads();
  if (threadIdx.x == 0) {
    __threadfence();                         // release: L2 writeback+inv
    atomicAdd(cnt, 1u);
    while (__hip_atomic_load(cnt, __ATOMIC_RELAXED,
                             __HIP_MEMORY_SCOPE_AGENT) < target) {
      __builtin_amdgcn_s_sleep(2);
    }
    __threadfence();                         // acquire: invalidate stale L2/L1
  }
  __syncthreads();
}

// ---------------------------------------------------------------------------
// R7 persistent LSTM layer. 32 blocks x 256 thr (regular launch; 32 <= 256
// CUs so co-residency is guaranteed). Wave mi = batches [mi*16,mi*16+16);
// block = units [U0,U0+16) x 4 gates. h ping-pongs X<->Y in bf16-split
// A-fragment layout hs[b][k=u]. Epilogue ALSO writes seqT hi/lo rows
// (t*64+b) directly (GEMM-A layout) — transpose kernels deleted.
// ---------------------------------------------------------------------------
__global__ __launch_bounds__(256)
void lstm_layer_persist(const float* __restrict__ Xg,
                        const ushort* __restrict__ WHi, const ushort* __restrict__ WLo,
                        float* __restrict__ cstate,
                        ushort* __restrict__ hXhi, ushort* __restrict__ hXlo,
                        ushort* __restrict__ hYhi, ushort* __restrict__ hYlo,
                        ushort* __restrict__ seqThi, ushort* __restrict__ seqTlo,
                        unsigned* __restrict__ cnt, int nsteps)
{
  const int tid = threadIdx.x;
  const int mi = tid >> 6;
  const int lane = tid & 63;
  const int lm = lane & 15, quad = lane >> 4;
  const int u = blockIdx.x * 16 + lm;
  const int koff = quad * 8;
  const int b0 = mi * 16 + quad * 4;

  const size_t aoff = (size_t)(mi * 16 + lm) * 512 + koff;
  const ushort* bH[4];
  const ushort* bL[4];
#pragma unroll
  for (int g = 0; g < 4; ++g) {
    const size_t o = (size_t)(g * 512 + u) * 512 + koff;
    bH[g] = WHi + o;
    bL[g] = WLo + o;
  }
  float* cptr = cstate + (size_t)u * 64 + b0;

  for (int t = 0; t < nsteps; ++t) {
    const ushort* aHi = ((t & 1) ? hYhi : hXhi) + aoff;
    const ushort* aLo = ((t & 1) ? hYlo : hXlo) + aoff;
    ushort* oHi = (t & 1) ? hXhi : hYhi;
    ushort* oLo = (t & 1) ? hXlo : hYlo;

    f32x4 acc[4];
#pragma unroll
    for (int g = 0; g < 4; ++g) acc[g] = (f32x4){0.f, 0.f, 0.f, 0.f};

#pragma unroll 4
    for (int k0 = 0; k0 < 512; k0 += 32) {
      const bf16x8 ah = *(const bf16x8*)(aHi + k0);
      const bf16x8 al = *(const bf16x8*)(aLo + k0);
#pragma unroll
      for (int g = 0; g < 4; ++g) {
        const bf16x8 bh = *(const bf16x8*)(bH[g] + k0);
        const bf16x8 bl = *(const bf16x8*)(bL[g] + k0);
        acc[g] = __builtin_amdgcn_mfma_f32_16x16x32_bf16(ah, bl, acc[g], 0, 0, 0);
        acc[g] = __builtin_amdgcn_mfma_f32_16x16x32_bf16(al, bh, acc[g], 0, 0, 0);
        acc[g] = __builtin_amdgcn_mfma_f32_16x16x32_bf16(ah, bh, acc[g], 0, 0, 0);
      }
    }

    // epilogue: lane owns unit u, batches b0..b0+3
    const float* Xt = Xg + (size_t)t * 131072;
    const float4 xi = *(const float4*)(Xt + (size_t)(0 * 512 + u) * 64 + b0);
    const float4 xf = *(const float4*)(Xt + (size_t)(1 * 512 + u) * 64 + b0);
    const float4 xg = *(const float4*)(Xt + (size_t)(2 * 512 + u) * 64 + b0);
    const float4 xo = *(const float4*)(Xt + (size_t)(3 * 512 + u) * 64 + b0);
    float4 c4 = *(float4*)cptr;

#pragma unroll
    for (int r = 0; r < 4; ++r) {
      const float zi = acc[0][r] + ((const float*)&xi)[r];
      const float zf = acc[1][r] + ((const float*)&xf)[r];
      const float zg = acc[2][r] + ((const float*)&xg)[r];
      const float zo = acc[3][r] + ((const float*)&xo)[r];
      const float I = 1.0f / (1.0f + expf(-zi));
      const float F = 1.0f / (1.0f + expf(-zf));
      const float G = tanhf(zg);
      const float O = 1.0f / (1.0f + expf(-zo));
      const float cn = F * ((float*)&c4)[r] + I * G;
      ((float*)&c4)[r] = cn;
      const float hv = O * tanhf(cn);
      const ushort hh = f2bf(hv);
      const ushort hl = f2bf(hv - bf2f(hh));
      oHi[(size_t)(b0 + r) * 512 + u] = hh;
      oLo[(size_t)(b0 + r) * 512 + u] = hl;
      if (seqThi) {
        const size_t srow = (size_t)(t * 64 + b0 + r) * 512 + u;
        seqThi[srow] = hh;
        seqTlo[srow] = hl;
      }
    }
    *(float4*)cptr = c4;

    if (t + 1 < nsteps) grid_bar(cnt, (unsigned)(t + 1) * 32u);
  }
}

// ---------------------------------------------------------------------------
__global__ void maskscan_kernel(const int* __restrict__ mask,
                                int* __restrict__ idxmap)
{
  const int b = threadIdx.x;   // 64 threads
  int run = 0;
  for (int t = 0; t < 128; ++t) {
    idxmap[b * 128 + t] = run;
    run += mask[b * 128 + t];
  }
}

__global__ __launch_bounds__(256)
void t0_kernel(const int* __restrict__ mask, unsigned long long* __restrict__ keys)
{
  const int b = blockIdx.x;
  const int row = b * 128;
  if (mask[row] == 0) return;
  const int tid = threadIdx.x;
  const uint32_t base = (uint32_t)b * 10000u;
  float best = -3.0e38f;
  int bestn = 0;
  for (int v = tid; v < 10000; v += 256) {
    const float u42 = jax_uniform(42u, base + (uint32_t)v);
    const float u7 = jax_uniform(7u, base + (uint32_t)v);
    const float g = -logf(-logf(u7 + 1e-20f) + 1e-20f);
    const float z = u42 + g;
    if (z > best) { best = z; bestn = v; }
  }
  __shared__ unsigned long long sk[256];
  sk[tid] = packkey(best, bestn);
  __syncthreads();
  for (int s = 128; s > 0; s >>= 1) {
    if (tid < s) { if (sk[tid + s] > sk[tid]) sk[tid] = sk[tid + s]; }
    __syncthreads();
  }
  if (tid == 0) keys[row] = sk[0];
}

__global__ __launch_bounds__(256)
void finalize_kernel(const unsigned long long* __restrict__ keys,
                     const int* __restrict__ mask,
                     const int* __restrict__ input_ids,
                     int* __restrict__ tokens)
{
  const int row = blockIdx.x * 256 + threadIdx.x;
  if (row < 8192) {
    tokens[row] = mask[row] ? (int)(0x7FFFFFFFu - (uint32_t)(keys[row] & 0xFFFFFFFFu))
                            : input_ids[row];
  }
}

__global__ __launch_bounds__(256)
void onehot_kernel(const int* __restrict__ tokens, float* __restrict__ out)
{
  const int row = blockIdx.x;
  const int tok = tokens[row];
  float4* orow = (float4*)(out + (size_t)row * 10000);
  for (int q = threadIdx.x; q < 2500; q += 256) {
    float4 v = make_float4(0.f, 0.f, 0.f, 0.f);
    const int v0 = q << 2;
    const unsigned d = (unsigned)(tok - v0);
    if (d < 4u) ((float*)&v)[d] = 1.0f;
    orow[q] = v;
  }
}

// ---------------------------------------------------------------------------
extern "C" void kernel_launch(void* const* d_in, const int* in_sizes, int n_in,
                              void* d_out, int out_size, void* d_ws, size_t ws_size,
                              hipStream_t stream)
{
  const int*   input_ids = (const int*)d_in[0];
  const int*   mask      = (const int*)d_in[1];
  const float* enc_embed = (const float*)d_in[3];
  const float* enc_Wih0  = (const float*)d_in[4];
  const float* enc_Whh0  = (const float*)d_in[5];
  const float* enc_b0    = (const float*)d_in[6];
  const float* enc_Wih1  = (const float*)d_in[7];
  const float* enc_Whh1  = (const float*)d_in[8];
  const float* enc_b1    = (const float*)d_in[9];
  const float* dec_embed = (const float*)d_in[10];
  const float* dec_Wih0  = (const float*)d_in[11];
  const float* dec_Whh0  = (const float*)d_in[12];
  const float* dec_b0    = (const float*)d_in[13];
  const float* dec_Wih1  = (const float*)d_in[14];
  const float* dec_Whh1  = (const float*)d_in[15];
  const float* dec_b1    = (const float*)d_in[16];
  const float* dec_Wout  = (const float*)d_in[17];
  const float* dec_bout  = (const float*)d_in[18];

  char* O = (char*)d_out;
  float*  Xg    = (float*)(O + OFF_XG);
  ushort* sThi  = (ushort*)(O + OFF_STHI);
  ushort* sTlo  = (ushort*)(O + OFF_STLO);
  ushort* eEh   = (ushort*)(O + OFF_EEH);
  ushort* eEl   = (ushort*)(O + OFF_EEL);
  ushort* dEh   = (ushort*)(O + OFF_DEH);
  ushort* dEl   = (ushort*)(O + OFF_DEL);
  ushort* eW0h  = (ushort*)(O + OFF_EW0H);
  ushort* eW0l  = (ushort*)(O + OFF_EW0L);
  ushort* eW1h  = (ushort*)(O + OFF_EW1H);
  ushort* eW1l  = (ushort*)(O + OFF_EW1L);
  ushort* dW0h  = (ushort*)(O + OFF_DW0H);
  ushort* dW0l  = (ushort*)(O + OFF_DW0L);
  ushort* dW1h  = (ushort*)(O + OFF_DW1H);
  ushort* dW1l  = (ushort*)(O + OFF_DW1L);
  ushort* Woh   = (ushort*)(O + OFF_WOH);
  ushort* Wol   = (ushort*)(O + OFF_WOL);
  unsigned long long* keys = (unsigned long long*)(O + OFF_KEYS);
  int*    idxmap = (int*)(O + OFF_IDXMAP);
  ushort* eH0h = (ushort*)(O + OFF_EH0H);
  ushort* eH0l = (ushort*)(O + OFF_EH0L);
  ushort* eH1h = (ushort*)(O + OFF_EH1H);
  ushort* eH1l = (ushort*)(O + OFF_EH1L);
  ushort* dH0h = (ushort*)(O + OFF_DH0H);
  ushort* dH0l = (ushort*)(O + OFF_DH0L);
  ushort* dH1h = (ushort*)(O + OFF_DH1H);
  ushort* dH1l = (ushort*)(O + OFF_DH1L);
  ushort* hsAhi = (ushort*)(O + OFF_HSA_HI);
  ushort* hsAlo = (ushort*)(O + OFF_HSA_LO);
  ushort* hsBhi = (ushort*)(O + OFF_HSB_HI);
  ushort* hsBlo = (ushort*)(O + OFF_HSB_LO);
  ushort* hsChi = (ushort*)(O + OFF_HSC_HI);
  ushort* hsClo = (ushort*)(O + OFF_HSC_LO);
  ushort* hsDhi = (ushort*)(O + OFF_HSD_HI);
  ushort* hsDlo = (ushort*)(O + OFF_HSD_LO);
  unsigned* bars = (unsigned*)(O + OFF_BARS);

  float* ws   = (float*)d_ws;
  float* cA   = ws;                       // 32768 floats (zeroed by prep)
  float* cB   = ws + 32768;               // 32768 floats (zeroed by prep)
  int* tokens = (int*)(ws + 65536);

  // ---- one kernel: all splits + all zero-inits ----
  prep_kernel<<<69505, 256, 0, stream>>>(O, ws,
      enc_embed, dec_embed, enc_Wih0, enc_Wih1, dec_Wih0, dec_Wih1,
      dec_Wout, enc_Whh0, enc_Whh1, dec_Whh0, dec_Whh1);
  maskscan_kernel<<<1, 64, 0, stream>>>(mask, idxmap);

  // ---- encoder layer 0: chain A<->B, final lands in A; writes seqT ----
  gemm_split<1, 0><<<dim3(64, 16), 256, 0, stream>>>(
      eEh, eEl, input_ids, eW0h, eW0l, enc_b0, Xg,
      nullptr, nullptr, nullptr, 8192, 2048, 256);
  lstm_layer_persist<<<32, 256, 0, stream>>>(
      Xg, eH0h, eH0l, cA, hsAhi, hsAlo, hsBhi, hsBlo, sThi, sTlo,
      bars + 0, 128);

  // ---- encoder layer 1: chain C<->D, final lands in C; no seq needed ----
  gemm_split<0, 0><<<dim3(64, 16), 256, 0, stream>>>(
      sThi, sTlo, nullptr, eW1h, eW1l, enc_b1, Xg,
      nullptr, nullptr, nullptr, 8192, 2048, 512);
  lstm_layer_persist<<<32, 256, 0, stream>>>(
      Xg, eH1h, eH1l, cB, hsChi, hsClo, hsDhi, hsDlo, nullptr, nullptr,
      bars + 1, 128);

  // ---- decoder layer 0: init h = enc L0 final (hsA), c = cA; 127 steps ----
  gemm_split<1, 0><<<dim3(64, 16), 256, 0, stream>>>(
      dEh, dEl, input_ids, dW0h, dW0l, dec_b0, Xg,
      nullptr, nullptr, nullptr, 8128, 2048, 256);
  lstm_layer_persist<<<32, 256, 0, stream>>>(
      Xg, dH0h, dH0l, cA, hsAhi, hsAlo, hsBhi, hsBlo, sThi, sTlo,
      bars + 2, 127);

  // ---- decoder layer 1: init h = enc L1 final (hsC), c = cB; 127 steps ----
  gemm_split<0, 0><<<dim3(64, 16), 256, 0, stream>>>(
      sThi, sTlo, nullptr, dW1h, dW1l, dec_b1, Xg,
      nullptr, nullptr, nullptr, 8128, 2048, 512);
  lstm_layer_persist<<<32, 256, 0, stream>>>(
      Xg, dH1h, dH1l, cB, hsChi, hsClo, hsDhi, hsDlo, sThi, sTlo,
      bars + 3, 127);

  // ---- fused logits + gumbel-argmax (no logits materialization) ----
  gemm_split<0, 1><<<dim3(64, 79), 256, 0, stream>>>(
      sThi, sTlo, nullptr, Woh, Wol, dec_bout, nullptr,
      mask, idxmap, keys, 8128, 10000, 512);
  t0_kernel<<<64, 256, 0, stream>>>(mask, keys);

  // ---- tokens -> one-hot output ----
  finalize_kernel<<<32, 256, 0, stream>>>(keys, mask, input_ids, tokens);
  onehot_kernel<<<8192, 256, 0, stream>>>(tokens, (float*)d_out);
}